// Round 1
// baseline (180.130 us; speedup 1.0000x reference)
//
#include <hip/hip_runtime.h>
#include <math.h>

#define HH 512
#define WW 512
#define KK 16
#define BB 64
#define HW (HH*WW)
#define CSTRIDE 40   // padded per-batch coeff stride (floats) for 16B alignment

// Kernel 1: build the 19x19 TPS system matrix, Gauss-Jordan invert (fp64,
// partial pivoting), then coeff[b][i][d] = sum_j inv[i][j] * sp[b][j][d].
// RBF rows (i<16) pre-scaled by ln(2) so kernel 2 can use hw log2.
__global__ __launch_bounds__(256) void tps_coeff_kernel(
    const float* __restrict__ sp, float* __restrict__ coeff) {
  __shared__ double A[19][38];
  __shared__ double f[19];
  __shared__ int pivrow;
  const double Xc[4] = {-1.0, -1.0/3.0, 1.0/3.0, 1.0};
  const int tid = threadIdx.x;

  // Build [delta | I]
  for (int idx = tid; idx < 19*38; idx += 256) {
    int r = idx / 38, c = idx % 38;
    double v;
    if (c >= 19) {
      v = ((c - 19) == r) ? 1.0 : 0.0;
    } else if (r < 16 && c < 16) {
      double dx = Xc[r>>2] - Xc[c>>2];
      double dy = Xc[r&3] - Xc[c&3];
      double r2 = dx*dx + dy*dy;
      v = r2 * log(r2 + 1e-6);
    } else if (r < 16) {
      v = (c == 16) ? 1.0 : ((c == 17) ? Xc[r>>2] : Xc[r&3]);
    } else if (c < 16) {
      v = (r == 16) ? 1.0 : ((r == 17) ? Xc[c>>2] : Xc[c&3]);
    } else {
      v = 0.0;
    }
    A[r][c] = v;
  }
  __syncthreads();

  // Gauss-Jordan with partial pivoting
  for (int k = 0; k < 19; ++k) {
    if (tid == 0) {
      int best = k; double bv = fabs(A[k][k]);
      for (int r = k + 1; r < 19; ++r) {
        double av = fabs(A[r][k]);
        if (av > bv) { bv = av; best = r; }
      }
      pivrow = best;
    }
    __syncthreads();
    int pr = pivrow;
    if (pr != k) {
      for (int c = tid; c < 38; c += 256) {
        double t = A[k][c]; A[k][c] = A[pr][c]; A[pr][c] = t;
      }
    }
    __syncthreads();
    double piv = A[k][k];
    if (tid < 19) f[tid] = A[tid][k];
    __syncthreads();
    double rp = 1.0 / piv;
    for (int c = tid; c < 38; c += 256) A[k][c] *= rp;
    __syncthreads();
    for (int idx = tid; idx < 19*38; idx += 256) {
      int r = idx / 38, c = idx % 38;
      if (r != k) A[r][c] -= f[r] * A[k][c];
    }
    __syncthreads();
  }

  // coeff: only j<16 contributes (Pm rows 16..18 are zero)
  const double LN2 = 0.6931471805599453;
  for (int idx = tid; idx < BB * 38; idx += 256) {
    int b = idx / 38, r = idx % 38;
    int i = r >> 1, d = r & 1;
    double s = 0.0;
    for (int j = 0; j < 16; ++j)
      s += A[i][19 + j] * (double)sp[(b * 16 + j) * 2 + d];
    if (i < 16) s *= LN2;  // fold ln2: kernel2 uses log2
    coeff[b * CSTRIDE + r] = (float)s;
  }
}

// Kernel 2: 2 pixels per thread, one batch per blockIdx.y.
__global__ __launch_bounds__(256) void tps_grid_kernel(
    const float* __restrict__ coeff, float* __restrict__ out) {
  const int b = blockIdx.y;
  const float* __restrict__ c = coeff + b * CSTRIDE;
  float cc[38];
#pragma unroll
  for (int i = 0; i < 38; ++i) cc[i] = c[i];

  const int n0 = (blockIdx.x * 256 + threadIdx.x) * 2;
  const int ix = n0 & (WW - 1);
  const int iy = n0 >> 9;
  const float step = 2.0f / 511.0f;
  const float gx0 = -1.0f + ix * step;
  const float gx1 = gx0 + step;
  const float gy  = -1.0f + iy * step;

  const float Xc[4] = {-1.0f, -1.0f/3.0f, 1.0f/3.0f, 1.0f};
  float dy2[4], dxa[4], dxb[4];
#pragma unroll
  for (int j = 0; j < 4; ++j) { float t = gy - Xc[j]; dy2[j] = t * t; }
#pragma unroll
  for (int i = 0; i < 4; ++i) {
    float t = gx0 - Xc[i]; dxa[i] = t * t + 1e-6f;  // fold eps here
    float u = gx1 - Xc[i]; dxb[i] = u * u + 1e-6f;
  }

  float a0x = cc[32] + gx0 * cc[34] + gy * cc[36];
  float a0y = cc[33] + gx0 * cc[35] + gy * cc[37];
  float a1x = cc[32] + gx1 * cc[34] + gy * cc[36];
  float a1y = cc[33] + gx1 * cc[35] + gy * cc[37];

#pragma unroll
  for (int k = 0; k < 16; ++k) {
    float t0 = dxa[k >> 2] + dy2[k & 3];
    float u0 = t0 * __log2f(t0);          // coeff pre-scaled by ln2
    a0x = fmaf(u0, cc[2 * k], a0x);
    a0y = fmaf(u0, cc[2 * k + 1], a0y);
    float t1 = dxb[k >> 2] + dy2[k & 3];
    float u1 = t1 * __log2f(t1);
    a1x = fmaf(u1, cc[2 * k], a1x);
    a1y = fmaf(u1, cc[2 * k + 1], a1y);
  }

  float4 v = make_float4(a0x, a0y, a1x, a1y);
  *(float4*)(out + (size_t)(b * HW + n0) * 2) = v;
}

extern "C" void kernel_launch(void* const* d_in, const int* in_sizes, int n_in,
                              void* d_out, int out_size, void* d_ws, size_t ws_size,
                              hipStream_t stream) {
  const float* sp = (const float*)d_in[0];   // [B, K, 2] fp32
  float* out = (float*)d_out;                // [B, H, W, 2] fp32
  float* coeff = (float*)d_ws;               // B * CSTRIDE floats

  tps_coeff_kernel<<<1, 256, 0, stream>>>(sp, coeff);

  dim3 grid(HW / 512, BB);  // 512 pixels per block (2 per thread), one b per y
  tps_grid_kernel<<<grid, 256, 0, stream>>>(coeff, out);
}

// Round 2
// 149.959 us; speedup vs baseline: 1.2012x; 1.2012x over previous
//
#include <hip/hip_runtime.h>

#define HH 512
#define WW 512
#define KK 16
#define BB 64
#define HW (HH*WW)

// ---------------------------------------------------------------------------
// Compile-time construction + inversion of the 19x19 TPS system matrix.
// All control points are constants, so inv_delta is a compile-time constant.
// RBF rows pre-scaled by ln(2) so the kernel can use hw v_log_f32 (log2).
// ---------------------------------------------------------------------------
constexpr double cx_ln(double x) {
  // range-reduce to [1,2), then atanh series: ln(m) = 2*sum z^(2k+1)/(2k+1)
  int e = 0;
  while (x >= 2.0) { x *= 0.5; ++e; }
  while (x < 1.0)  { x *= 2.0; --e; }
  double z = (x - 1.0) / (x + 1.0);
  double z2 = z * z, term = z, sum = 0.0;
  for (int n = 1; n < 60; n += 2) { sum += term / n; term *= z2; }
  return 2.0 * sum + e * 0.69314718055994530942;
}

struct WMat { float w[19][16]; };

constexpr WMat build_wm() {
  const double Xc[4] = {-1.0, -1.0/3.0, 1.0/3.0, 1.0};
  double A[19][38] = {};
  // [delta | I]
  for (int r = 0; r < 19; ++r) {
    for (int c = 0; c < 38; ++c) {
      double v = 0.0;
      if (c >= 19) {
        v = ((c - 19) == r) ? 1.0 : 0.0;
      } else if (r < 16 && c < 16) {
        double dx = Xc[r >> 2] - Xc[c >> 2];
        double dy = Xc[r & 3] - Xc[c & 3];
        double r2 = dx * dx + dy * dy;
        v = (r2 == 0.0) ? 0.0 : r2 * cx_ln(r2 + 1e-6);
      } else if (r < 16) {
        v = (c == 16) ? 1.0 : ((c == 17) ? Xc[r >> 2] : Xc[r & 3]);
      } else if (c < 16) {
        v = (r == 16) ? 1.0 : ((r == 17) ? Xc[c >> 2] : Xc[c & 3]);
      }
      A[r][c] = v;
    }
  }
  // Gauss-Jordan with partial pivoting (fp64)
  for (int k = 0; k < 19; ++k) {
    int best = k;
    double bv = A[k][k] < 0 ? -A[k][k] : A[k][k];
    for (int r = k + 1; r < 19; ++r) {
      double av = A[r][k] < 0 ? -A[r][k] : A[r][k];
      if (av > bv) { bv = av; best = r; }
    }
    if (best != k)
      for (int c = 0; c < 38; ++c) { double t = A[k][c]; A[k][c] = A[best][c]; A[best][c] = t; }
    double rp = 1.0 / A[k][k];
    for (int c = 0; c < 38; ++c) A[k][c] *= rp;
    for (int r = 0; r < 19; ++r) {
      if (r == k) continue;
      double f = A[r][k];
      for (int c = 0; c < 38; ++c) A[r][c] -= f * A[k][c];
    }
  }
  // Only columns 0..15 of inv_delta matter (Pm rows 16..18 are zero).
  // Pre-scale RBF rows (i<16) by ln2 so kernel uses log2.
  WMat wm = {};
  for (int i = 0; i < 19; ++i)
    for (int j = 0; j < 16; ++j)
      wm.w[i][j] = (float)(A[i][19 + j] * (i < 16 ? 0.69314718055994530942 : 1.0));
  return wm;
}

__device__ __constant__ WMat WM = build_wm();

// ---------------------------------------------------------------------------
// Single fused kernel: 38 lanes compute the per-batch coeffs (tiny matvec
// against the baked inverse), LDS-broadcast, then 4 pixels per thread.
// ---------------------------------------------------------------------------
__global__ __launch_bounds__(256) void tps_grid_kernel(
    const float* __restrict__ sp, float* __restrict__ out) {
  __shared__ float cs[40];
  const int tid = threadIdx.x;
  const int b = blockIdx.y;

  if (tid < 38) {
    const int i = tid >> 1, d = tid & 1;
    const float* s = sp + b * 32 + d;
    float acc = 0.0f;
#pragma unroll
    for (int j = 0; j < 16; ++j) acc = fmaf(WM.w[i][j], s[2 * j], acc);
    cs[tid] = acc;
  }
  __syncthreads();

  // Broadcast coeffs from LDS via vector reads (all indices constant -> regs)
  float cc[38];
#pragma unroll
  for (int i = 0; i < 9; ++i) {
    float4 t = ((const float4*)cs)[i];
    cc[4 * i] = t.x; cc[4 * i + 1] = t.y; cc[4 * i + 2] = t.z; cc[4 * i + 3] = t.w;
  }
  cc[36] = cs[36]; cc[37] = cs[37];

  const int n0 = (blockIdx.x * 256 + tid) * 4;   // 4 consecutive pixels, same row
  const int ix = n0 & (WW - 1);
  const int iy = n0 >> 9;
  const float step = 2.0f / 511.0f;
  const float gy = -1.0f + iy * step;
  const float Xc[4] = {-1.0f, -1.0f / 3.0f, 1.0f / 3.0f, 1.0f};

  float dy2[4];
#pragma unroll
  for (int j = 0; j < 4; ++j) { float t = gy - Xc[j]; dy2[j] = t * t; }

  float gx[4], dx2[4][4];
#pragma unroll
  for (int p = 0; p < 4; ++p) {
    gx[p] = -1.0f + (ix + p) * step;
#pragma unroll
    for (int i = 0; i < 4; ++i) {
      float t = gx[p] - Xc[i];
      dx2[p][i] = fmaf(t, t, 1e-6f);   // fold eps here (dy2 has none)
    }
  }

  float ax[4], ay[4];
#pragma unroll
  for (int p = 0; p < 4; ++p) {
    ax[p] = cc[32] + gx[p] * cc[34] + gy * cc[36];
    ay[p] = cc[33] + gx[p] * cc[35] + gy * cc[37];
  }

#pragma unroll
  for (int k = 0; k < 16; ++k) {
    const float wx = cc[2 * k], wy = cc[2 * k + 1];
#pragma unroll
    for (int p = 0; p < 4; ++p) {
      float t = dx2[p][k >> 2] + dy2[k & 3];
      float u = t * __log2f(t);        // coeff pre-scaled by ln2
      ax[p] = fmaf(u, wx, ax[p]);
      ay[p] = fmaf(u, wy, ay[p]);
    }
  }

  float* o = out + (size_t)(b * HW + n0) * 2;
  *(float4*)o       = make_float4(ax[0], ay[0], ax[1], ay[1]);
  *((float4*)o + 1) = make_float4(ax[2], ay[2], ax[3], ay[3]);
}

extern "C" void kernel_launch(void* const* d_in, const int* in_sizes, int n_in,
                              void* d_out, int out_size, void* d_ws, size_t ws_size,
                              hipStream_t stream) {
  const float* sp = (const float*)d_in[0];   // [B, K, 2] fp32
  float* out = (float*)d_out;                // [B, H, W, 2] fp32

  dim3 grid(HW / 1024, BB);                  // 1024 pixels per block (4/thread)
  tps_grid_kernel<<<grid, 256, 0, stream>>>(sp, out);
}

// Round 3
// 147.393 us; speedup vs baseline: 1.2221x; 1.0174x over previous
//
#include <hip/hip_runtime.h>

#define HH 512
#define WW 512
#define BB 64
#define HW (HH*WW)

typedef float v2f __attribute__((ext_vector_type(2)));

// ---------------------------------------------------------------------------
// Compile-time construction + inversion of the 19x19 TPS system matrix.
// RBF rows pre-scaled by ln(2) so the kernel can use hw v_log_f32 (log2).
// ---------------------------------------------------------------------------
constexpr double cx_ln(double x) {
  int e = 0;
  while (x >= 2.0) { x *= 0.5; ++e; }
  while (x < 1.0)  { x *= 2.0; --e; }
  double z = (x - 1.0) / (x + 1.0);
  double z2 = z * z, term = z, sum = 0.0;
  for (int n = 1; n < 60; n += 2) { sum += term / n; term *= z2; }
  return 2.0 * sum + e * 0.69314718055994530942;
}

struct WMat { float w[19][16]; };

constexpr WMat build_wm() {
  const double Xc[4] = {-1.0, -1.0/3.0, 1.0/3.0, 1.0};
  double A[19][38] = {};
  for (int r = 0; r < 19; ++r) {
    for (int c = 0; c < 38; ++c) {
      double v = 0.0;
      if (c >= 19) {
        v = ((c - 19) == r) ? 1.0 : 0.0;
      } else if (r < 16 && c < 16) {
        double dx = Xc[r >> 2] - Xc[c >> 2];
        double dy = Xc[r & 3] - Xc[c & 3];
        double r2 = dx * dx + dy * dy;
        v = (r2 == 0.0) ? 0.0 : r2 * cx_ln(r2 + 1e-6);
      } else if (r < 16) {
        v = (c == 16) ? 1.0 : ((c == 17) ? Xc[r >> 2] : Xc[r & 3]);
      } else if (c < 16) {
        v = (r == 16) ? 1.0 : ((r == 17) ? Xc[c >> 2] : Xc[c & 3]);
      }
      A[r][c] = v;
    }
  }
  for (int k = 0; k < 19; ++k) {
    int best = k;
    double bv = A[k][k] < 0 ? -A[k][k] : A[k][k];
    for (int r = k + 1; r < 19; ++r) {
      double av = A[r][k] < 0 ? -A[r][k] : A[r][k];
      if (av > bv) { bv = av; best = r; }
    }
    if (best != k)
      for (int c = 0; c < 38; ++c) { double t = A[k][c]; A[k][c] = A[best][c]; A[best][c] = t; }
    double rp = 1.0 / A[k][k];
    for (int c = 0; c < 38; ++c) A[k][c] *= rp;
    for (int r = 0; r < 19; ++r) {
      if (r == k) continue;
      double f = A[r][k];
      for (int c = 0; c < 38; ++c) A[r][c] -= f * A[k][c];
    }
  }
  WMat wm = {};
  for (int i = 0; i < 19; ++i)
    for (int j = 0; j < 16; ++j)
      wm.w[i][j] = (float)(A[i][19 + j] * (i < 16 ? 0.69314718055994530942 : 1.0));
  return wm;
}

__device__ __constant__ WMat WM = build_wm();

__device__ __forceinline__ float fast_log2(float x) {
#if __has_builtin(__builtin_amdgcn_logf)
  return __builtin_amdgcn_logf(x);   // raw v_log_f32
#else
  return __log2f(x);
#endif
}

// ---------------------------------------------------------------------------
// Fused kernel: lanes<38 compute per-batch coeffs (matvec vs baked inverse),
// LDS-broadcast, then 4 pixels/thread with packed-fp32 (v_pk_*) inner loop.
// ---------------------------------------------------------------------------
__global__ __launch_bounds__(256) void tps_grid_kernel(
    const float* __restrict__ sp, float* __restrict__ out) {
  __shared__ float cs[40];
  const int tid = threadIdx.x;
  const int b = blockIdx.y;

  if (tid < 38) {
    const int i = tid >> 1, d = tid & 1;
    const float* s = sp + b * 32 + d;
    float acc = 0.0f;
#pragma unroll
    for (int j = 0; j < 16; ++j) acc = fmaf(WM.w[i][j], s[2 * j], acc);
    cs[tid] = acc;
  }
  __syncthreads();

  // coefficient pairs {x,y}: w[k] = RBF weight pair, aff* = affine pairs
  v2f w[16];
#pragma unroll
  for (int k = 0; k < 16; ++k) w[k] = ((const v2f*)cs)[k];
  const v2f aff0 = ((const v2f*)cs)[16];  // {c,  c }
  const v2f affx = ((const v2f*)cs)[17];  // {ax, ay} for gx
  const v2f affy = ((const v2f*)cs)[18];  // {bx, by} for gy

  const int n0 = (blockIdx.x * 256 + tid) * 4;  // 4 consecutive px, same row
  const int ix = n0 & (WW - 1);
  const int iy = n0 >> 9;
  const float step = 2.0f / 511.0f;
  const float gy = -1.0f + iy * step;
  const float Xc[4] = {-1.0f, -1.0f / 3.0f, 1.0f / 3.0f, 1.0f};

  float dy2[4];
#pragma unroll
  for (int j = 0; j < 4; ++j) { float t = gy - Xc[j]; dy2[j] = t * t; }

  float gx[4];
#pragma unroll
  for (int p = 0; p < 4; ++p) gx[p] = -1.0f + (ix + p) * step;

  // dx2 for pixel pairs: dx2p[h][i] = {dx2(px 2h, cp i), dx2(px 2h+1, cp i)}
  v2f dx2p[2][4];
#pragma unroll
  for (int h = 0; h < 2; ++h)
#pragma unroll
    for (int i = 0; i < 4; ++i) {
      float t0 = gx[2 * h] - Xc[i];
      float t1 = gx[2 * h + 1] - Xc[i];
      dx2p[h][i] = (v2f){fmaf(t0, t0, 1e-6f), fmaf(t1, t1, 1e-6f)};  // eps folded
    }

  v2f acc[4];
#pragma unroll
  for (int p = 0; p < 4; ++p) acc[p] = aff0 + gx[p] * affx + gy * affy;

#pragma unroll
  for (int k = 0; k < 16; ++k) {
    const int i = k >> 2, j = k & 3;
    v2f t01 = dx2p[0][i] + dy2[j];          // v_pk_add_f32
    v2f t23 = dx2p[1][i] + dy2[j];
    float l0 = fast_log2(t01.x);
    float l1 = fast_log2(t01.y);
    float l2 = fast_log2(t23.x);
    float l3 = fast_log2(t23.y);
    v2f u01 = t01 * (v2f){l0, l1};          // v_pk_mul_f32 (coeff has ln2)
    v2f u23 = t23 * (v2f){l2, l3};
    acc[0] += w[k] * u01.x;                 // v_pk_fma_f32 each
    acc[1] += w[k] * u01.y;
    acc[2] += w[k] * u23.x;
    acc[3] += w[k] * u23.y;
  }

  float* o = out + (size_t)(b * HW + n0) * 2;
  *(float4*)o       = make_float4(acc[0].x, acc[0].y, acc[1].x, acc[1].y);
  ((float4*)o)[1]   = make_float4(acc[2].x, acc[2].y, acc[3].x, acc[3].y);
}

extern "C" void kernel_launch(void* const* d_in, const int* in_sizes, int n_in,
                              void* d_out, int out_size, void* d_ws, size_t ws_size,
                              hipStream_t stream) {
  const float* sp = (const float*)d_in[0];   // [B, K, 2] fp32
  float* out = (float*)d_out;                // [B, H, W, 2] fp32

  dim3 grid(HW / 1024, BB);                  // 1024 px per block (4/thread)
  tps_grid_kernel<<<grid, 256, 0, stream>>>(sp, out);
}

// Round 5
// 140.705 us; speedup vs baseline: 1.2802x; 1.0475x over previous
//
#include <hip/hip_runtime.h>

#define HH 512
#define WW 512
#define BB 64
#define HW (HH*WW)
#define CSTRIDE 40     // padded per-batch coeff stride (floats)
#define BGRP 16        // batches per block (4 y-groups)

typedef float v2f __attribute__((ext_vector_type(2)));
typedef float v4f __attribute__((ext_vector_type(4)));

// ---------------------------------------------------------------------------
// Compile-time construction + inversion of the 19x19 TPS system matrix.
// RBF rows pre-scaled by ln(2) so the kernel can use hw v_log_f32 (log2).
// ---------------------------------------------------------------------------
constexpr double cx_ln(double x) {
  int e = 0;
  while (x >= 2.0) { x *= 0.5; ++e; }
  while (x < 1.0)  { x *= 2.0; --e; }
  double z = (x - 1.0) / (x + 1.0);
  double z2 = z * z, term = z, sum = 0.0;
  for (int n = 1; n < 60; n += 2) { sum += term / n; term *= z2; }
  return 2.0 * sum + e * 0.69314718055994530942;
}

struct WMat { float w[19][16]; };

constexpr WMat build_wm() {
  const double Xc[4] = {-1.0, -1.0/3.0, 1.0/3.0, 1.0};
  double A[19][38] = {};
  for (int r = 0; r < 19; ++r) {
    for (int c = 0; c < 38; ++c) {
      double v = 0.0;
      if (c >= 19) {
        v = ((c - 19) == r) ? 1.0 : 0.0;
      } else if (r < 16 && c < 16) {
        double dx = Xc[r >> 2] - Xc[c >> 2];
        double dy = Xc[r & 3] - Xc[c & 3];
        double r2 = dx * dx + dy * dy;
        v = (r2 == 0.0) ? 0.0 : r2 * cx_ln(r2 + 1e-6);
      } else if (r < 16) {
        v = (c == 16) ? 1.0 : ((c == 17) ? Xc[r >> 2] : Xc[r & 3]);
      } else if (c < 16) {
        v = (r == 16) ? 1.0 : ((r == 17) ? Xc[c >> 2] : Xc[c & 3]);
      }
      A[r][c] = v;
    }
  }
  for (int k = 0; k < 19; ++k) {
    int best = k;
    double bv = A[k][k] < 0 ? -A[k][k] : A[k][k];
    for (int r = k + 1; r < 19; ++r) {
      double av = A[r][k] < 0 ? -A[r][k] : A[r][k];
      if (av > bv) { bv = av; best = r; }
    }
    if (best != k)
      for (int c = 0; c < 38; ++c) { double t = A[k][c]; A[k][c] = A[best][c]; A[best][c] = t; }
    double rp = 1.0 / A[k][k];
    for (int c = 0; c < 38; ++c) A[k][c] *= rp;
    for (int r = 0; r < 19; ++r) {
      if (r == k) continue;
      double f = A[r][k];
      for (int c = 0; c < 38; ++c) A[r][c] -= f * A[k][c];
    }
  }
  WMat wm = {};
  for (int i = 0; i < 19; ++i)
    for (int j = 0; j < 16; ++j)
      wm.w[i][j] = (float)(A[i][19 + j] * (i < 16 ? 0.69314718055994530942 : 1.0));
  return wm;
}

__device__ __constant__ WMat WM = build_wm();

__device__ __forceinline__ float fast_log2(float x) {
#if __has_builtin(__builtin_amdgcn_logf)
  return __builtin_amdgcn_logf(x);
#else
  return __log2f(x);
#endif
}

// ---------------------------------------------------------------------------
// Kernel 1: per-batch coefficients -> d_ws. Block b, lanes<38 each do a
// 16-length dot against the baked inverse.
// ---------------------------------------------------------------------------
__global__ __launch_bounds__(64) void tps_coeff_kernel(
    const float* __restrict__ sp, float* __restrict__ coeff) {
  const int b = blockIdx.x;
  const int tid = threadIdx.x;
  if (tid < 38) {
    const int i = tid >> 1, d = tid & 1;
    const float* s = sp + b * 32 + d;
    float acc = 0.0f;
#pragma unroll
    for (int j = 0; j < 16; ++j) acc = fmaf(WM.w[i][j], s[2 * j], acc);
    coeff[b * CSTRIDE + tid] = acc;
  }
}

// ---------------------------------------------------------------------------
// Kernel 2: each thread owns 2 adjacent pixels; computes the batch-
// independent RBF basis u[16] ONCE, then loops over BGRP batches doing only
// pk_fma against wave-uniform coefficients (scalar loads from d_ws).
// ---------------------------------------------------------------------------
__global__ __launch_bounds__(256) void tps_grid_kernel(
    const float* __restrict__ coeff, float* __restrict__ out) {
  const int n0 = (blockIdx.x * 256 + threadIdx.x) * 2;  // 2 adjacent px, same row
  const int ix = n0 & (WW - 1);
  const int iy = n0 >> 9;
  const float step = 2.0f / 511.0f;
  const float gy = -1.0f + iy * step;
  const v2f gxv = {-1.0f + ix * step, -1.0f + (ix + 1) * step};
  const float Xc[4] = {-1.0f, -1.0f / 3.0f, 1.0f / 3.0f, 1.0f};

  float dy2[4];
#pragma unroll
  for (int j = 0; j < 4; ++j) { float t = gy - Xc[j]; dy2[j] = t * t; }

  v2f dxp[4];
#pragma unroll
  for (int i = 0; i < 4; ++i) {
    v2f t = gxv - Xc[i];
    dxp[i] = t * t + 1e-6f;   // eps folded here (dy2 has none)
  }

  // batch-independent RBF basis, pixel-pair packed: u2[k] = {u_k(px0), u_k(px1)}
  v2f u2[16];
#pragma unroll
  for (int k = 0; k < 16; ++k) {
    v2f t = dxp[k >> 2] + dy2[k & 3];           // v_pk_add_f32
    u2[k] = t * (v2f){fast_log2(t.x), fast_log2(t.y)};  // 2 logs + pk_mul
  }

  const int b0 = blockIdx.y * BGRP;
  for (int bi = 0; bi < BGRP; ++bi) {
    const int b = b0 + bi;
    const float* __restrict__ c = coeff + b * CSTRIDE;  // wave-uniform address
    float cc[38];
#pragma unroll
    for (int i = 0; i < 38; ++i) cc[i] = c[i];          // uniform -> s_load

    v2f accx = cc[32] + gxv * cc[34] + gy * cc[36];     // {x(px0), x(px1)}
    v2f accy = cc[33] + gxv * cc[35] + gy * cc[37];
#pragma unroll
    for (int k = 0; k < 16; ++k) {
      accx += u2[k] * cc[2 * k];                        // v_pk_fma, SGPR coeff
      accy += u2[k] * cc[2 * k + 1];
    }

    v4f v = {accx.x, accy.x, accx.y, accy.y};
    __builtin_nontemporal_store(v, (v4f*)(out + (size_t)(b * HW + n0) * 2));
  }
}

extern "C" void kernel_launch(void* const* d_in, const int* in_sizes, int n_in,
                              void* d_out, int out_size, void* d_ws, size_t ws_size,
                              hipStream_t stream) {
  const float* sp = (const float*)d_in[0];   // [B, K, 2] fp32
  float* out = (float*)d_out;                // [B, H, W, 2] fp32
  float* coeff = (float*)d_ws;               // BB * CSTRIDE floats

  tps_coeff_kernel<<<BB, 64, 0, stream>>>(sp, coeff);

  dim3 grid(HW / 512, BB / BGRP);            // 512 px per block x, 4 batch-groups y
  tps_grid_kernel<<<grid, 256, 0, stream>>>(coeff, out);
}